// Round 10
// baseline (379.646 us; speedup 1.0000x reference)
//
#include <hip/hip_runtime.h>
#include <math.h>

#define N_PTS 16384
#define DIMS 256
#define HEADS 8
#define HDIM 32
#define KNN 20
#define MLPH 1024
#define NSHARD 128
#define SHARDC 128
#define SURV_SLOTS 64
#define SCALE 0.17677669529663687f  // 32^-0.5

typedef unsigned short u16;
typedef unsigned long long ull;
typedef __attribute__((ext_vector_type(8))) short bf16x8;
typedef __attribute__((ext_vector_type(8))) unsigned short u16x8;
typedef __attribute__((ext_vector_type(4))) float f32x4;

__device__ __forceinline__ float bf2f(u16 u) {
  return __uint_as_float(((unsigned int)u) << 16);
}
__device__ __forceinline__ u16 f2bf(float f) {
  unsigned int u = __float_as_uint(f);
  u += 0x7fffu + ((u >> 16) & 1u);
  return (u16)(u >> 16);
}
// finite-scrub: NaN/Inf -> 0 (cheap insurance)
__device__ __forceinline__ float fin(float v) {
  return __builtin_isfinite(v) ? v : 0.f;
}
__device__ __forceinline__ float dist2(float4 a, float4 b) {
  float dx = a.x - b.x, dy = a.y - b.y, dz = a.z - b.z;
  return dx * dx + dy * dy + dz * dz;
}
__device__ __forceinline__ u16x8 cvt8(float4 a, float4 b) {
  u16x8 o;
  o[0] = f2bf(a.x); o[1] = f2bf(a.y); o[2] = f2bf(a.z); o[3] = f2bf(a.w);
  o[4] = f2bf(b.x); o[5] = f2bf(b.y); o[6] = f2bf(b.z); o[7] = f2bf(b.w);
  return o;
}
// async global->LDS, 16 B per lane; LDS dest must be wave-uniform base +
// lane*16 (our lane-linear t*16 layout satisfies this).
__device__ __forceinline__ void gld16(const u16* g, u16* l) {
  __builtin_amdgcn_global_load_lds(
      (const __attribute__((address_space(1))) unsigned int*)g,
      (__attribute__((address_space(3))) unsigned int*)l, 16, 0, 0);
}

// ---------------- init (zero cnt+nbr) + prep_pos fused ----------------

__global__ __launch_bounds__(256) void knn_init(const float* __restrict__ pos,
                                                float4* __restrict__ pos4,
                                                int* __restrict__ cnt,
                                                int* __restrict__ nbr) {
  int i = blockIdx.x * 256 + threadIdx.x;  // i < N_PTS
  cnt[i] = 0;
#pragma unroll
  for (int j = 0; j < KNN; ++j) nbr[i * KNN + j] = 0;
  float x = fin(pos[3 * i]), y = fin(pos[3 * i + 1]), z = fin(pos[3 * i + 2]);
  pos4[i] = make_float4(x, y, z, x * x + y * y + z * z);
}

// ---------------- weight pre-convert: Wq/Wk/Wv/Wo f32 -> bf16 ----------------
// 4 x 65536 elements; lives in the dead-after-tau Mmin region.

__global__ __launch_bounds__(256) void conv_w(const float* __restrict__ Wq,
                                              const float* __restrict__ Wk,
                                              const float* __restrict__ Wv,
                                              const float* __restrict__ Wo,
                                              u16* __restrict__ wbf) {
  int idx = blockIdx.x * 256 + threadIdx.x;  // 0..65535 float4-groups
  int mat = idx >> 14, loc = idx & 16383;
  const float* src = (mat == 0) ? Wq : ((mat == 1) ? Wk : ((mat == 2) ? Wv : Wo));
  float4 v = ((const float4*)src)[loc];
  ushort4 o;
  o.x = f2bf(v.x); o.y = f2bf(v.y); o.z = f2bf(v.z); o.w = f2bf(v.w);
  ((ushort4*)(wbf + mat * 65536))[loc] = o;
}

// ---------------- kNN ----------------
// pos4.w holds |c|^2; screening metric d' = |c|^2 - 2 q.c (per-query shift
// of true d — order statistics per query unaffected). 128 shards: at most
// 20 shard-minima can be < d_(21), so tau = 21st-smallest shard-min >= d_(21).

// grid (128 shards, 16 q-groups), block 256, 4 queries/thread.
__global__ __launch_bounds__(256) void knn_shardmin(const float4* __restrict__ pos4,
                                                    float* __restrict__ Mmin) {
  __shared__ float4 cp[SHARDC];
  int shard = blockIdx.x;
  int qbase = blockIdx.y * 1024 + threadIdx.x;
  if (threadIdx.x < SHARDC) cp[threadIdx.x] = pos4[shard * SHARDC + threadIdx.x];
  float m2x[4], m2y[4], m2z[4], mn[4];
#pragma unroll
  for (int k = 0; k < 4; ++k) {
    float4 qp = pos4[qbase + k * 256];
    m2x[k] = -2.f * qp.x; m2y[k] = -2.f * qp.y; m2z[k] = -2.f * qp.z;
    mn[k] = 3.4e38f;
  }
  __syncthreads();
#pragma unroll 4
  for (int c = 0; c < SHARDC; ++c) {
    float4 cc = cp[c];
#pragma unroll
    for (int k = 0; k < 4; ++k) {
      float t = fmaf(m2z[k], cc.z, cc.w);
      t = fmaf(m2y[k], cc.y, t);
      t = fmaf(m2x[k], cc.x, t);
      mn[k] = fminf(mn[k], t);
    }
  }
#pragma unroll
  for (int k = 0; k < 4; ++k) Mmin[shard * N_PTS + qbase + k * 256] = mn[k];
}

// tau[q] = 21st smallest of the 128 shard minima (d' metric)
__global__ __launch_bounds__(256) void knn_tau(const float* __restrict__ Mmin,
                                               float* __restrict__ tau) {
  int q = blockIdx.x * 256 + threadIdx.x;
  float a[21];
#pragma unroll
  for (int j = 0; j < 21; ++j) a[j] = 3.4e38f;
  for (int s = 0; s < NSHARD; ++s) {
    float v = Mmin[s * N_PTS + q];
    a[20] = fminf(a[20], v);
#pragma unroll
    for (int j = 20; j >= 1; --j) {  // sink pass restores sortedness
      float lo = fminf(a[j - 1], a[j]), hi = fmaxf(a[j - 1], a[j]);
      a[j - 1] = lo; a[j] = hi;
    }
  }
  tau[q] = a[20];
}

// grid (128 cand-shards, 16 q-groups), block 256, 4 queries/thread.
// Branchless hot loop (r8 lesson), 3-op if-converted record (r9):
//   packed = hit ? (packed<<8)|c : packed;  hitcnt += hit;
// Cold path materializes exact keys post-loop; hitcnt>4 rescans.
__global__ __launch_bounds__(256) void knn_collect(const float4* __restrict__ pos4,
                                                   const float* __restrict__ tau,
                                                   int* __restrict__ cnt,
                                                   ull* __restrict__ surv) {
  __shared__ float4 cp[SHARDC];
  int cbase = blockIdx.x * SHARDC;
  int qbase = blockIdx.y * 1024 + threadIdx.x;
  if (threadIdx.x < SHARDC) cp[threadIdx.x] = pos4[cbase + threadIdx.x];
  float4 qp[4];
  float m2x[4], m2y[4], m2z[4], tq[4];
  unsigned int packed[4];
  int hitcnt[4];
#pragma unroll
  for (int k = 0; k < 4; ++k) {
    qp[k] = pos4[qbase + k * 256];
    m2x[k] = -2.f * qp[k].x; m2y[k] = -2.f * qp[k].y; m2z[k] = -2.f * qp[k].z;
    tq[k] = tau[qbase + k * 256] + 2e-4f;  // slack >> worst-case fma rounding
    packed[k] = 0; hitcnt[k] = 0;
  }
  __syncthreads();
#pragma unroll 4
  for (int c = 0; c < SHARDC; ++c) {
    float4 cc = cp[c];
#pragma unroll
    for (int k = 0; k < 4; ++k) {
      float t = fmaf(m2z[k], cc.z, cc.w);
      t = fmaf(m2y[k], cc.y, t);
      t = fmaf(m2x[k], cc.x, t);
      bool hit = (t <= tq[k]);
      packed[k] = hit ? ((packed[k] << 8) | (unsigned)c) : packed[k];
      hitcnt[k] += hit ? 1 : 0;
    }
  }
  // cold path: materialize keys for recorded hits
#pragma unroll
  for (int k = 0; k < 4; ++k) {
    int hc = hitcnt[k];
    if (hc > 0) {
      int q = qbase + k * 256;
      if (hc <= 4) {
        int slot = atomicAdd(&cnt[q], hc);
        for (int i = 0; i < hc; ++i) {
          int c = (packed[k] >> (8 * i)) & 255;
          float d = dist2(qp[k], cp[c]);  // exact key, same as r4-passing
          ull key = ((ull)__float_as_uint(d) << 32) | (unsigned)(cbase + c);
          if (slot + i < SURV_SLOTS)
            surv[(size_t)q * SURV_SLOTS + slot + i] = key;
        }
      } else {  // overflow: packed lost early hits -> rescan this query
        for (int c = 0; c < SHARDC; ++c) {
          float4 cc = cp[c];
          float t = fmaf(m2z[k], cc.z, cc.w);
          t = fmaf(m2y[k], cc.y, t);
          t = fmaf(m2x[k], cc.x, t);
          if (t <= tq[k]) {
            float d = dist2(qp[k], cc);
            ull key = ((ull)__float_as_uint(d) << 32) | (unsigned)(cbase + c);
            int slot = atomicAdd(&cnt[q], 1);
            if (slot < SURV_SLOTS) surv[(size_t)q * SURV_SLOTS + slot] = key;
          }
        }
      }
    }
  }
}

// block = 64 threads per query: rank survivors; ranks 1..20 -> neighbor list
__global__ void knn_rank(const int* __restrict__ cnt,
                         const ull* __restrict__ surv,
                         int* __restrict__ nbr) {
  __shared__ ull s[SURV_SLOTS];
  int q = blockIdx.x;
  int c = min(cnt[q], SURV_SLOTS);
  for (int i = threadIdx.x; i < c; i += 64) s[i] = surv[(size_t)q * SURV_SLOTS + i];
  __syncthreads();
  for (int i = threadIdx.x; i < c; i += 64) {
    ull key = s[i];
    int rank = 0;
    for (int j = 0; j < c; ++j) rank += (s[j] < key);
    if (rank >= 1 && rank <= KNN) nbr[q * KNN + rank - 1] = (int)(key & 0xffffffffu);
  }
}

// ---------------- LayerNorm (wave per row, 256 cols): f32 in -> bf16 out ----

__global__ __launch_bounds__(256) void ln_kernel(const float* __restrict__ xin,
                                                 const float* __restrict__ w,
                                                 const float* __restrict__ b,
                                                 u16* __restrict__ out) {
  int row = blockIdx.x * 4 + (threadIdx.x >> 6);
  int lane = threadIdx.x & 63;
  float4 u = ((const float4*)(xin + row * DIMS))[lane];
  float f[4] = {fin(u.x), fin(u.y), fin(u.z), fin(u.w)};
  float sum = f[0] + f[1] + f[2] + f[3];
  float sq = f[0] * f[0] + f[1] * f[1] + f[2] * f[2] + f[3] * f[3];
#pragma unroll
  for (int o = 32; o > 0; o >>= 1) {
    sum += __shfl_xor(sum, o);
    sq += __shfl_xor(sq, o);
  }
  float mean = sum * (1.f / 256.f);
  float var = fmaxf(sq * (1.f / 256.f) - mean * mean, 0.f);  // guard
  float rs = rsqrtf(var + 1e-5f);
  float4 wv = ((const float4*)w)[lane];
  float4 bv = ((const float4*)b)[lane];
  ushort4 o4;
  o4.x = f2bf(fin((f[0] - mean) * rs * wv.x + bv.x));
  o4.y = f2bf(fin((f[1] - mean) * rs * wv.y + bv.y));
  o4.z = f2bf(fin((f[2] - mean) * rs * wv.z + bv.z));
  o4.w = f2bf(fin((f[3] - mean) * rs * wv.w + bv.w));
  ((ushort4*)(out + row * DIMS))[lane] = o4;
}

// ---------------- MFMA GEMM body ----------------
// C[M,Nc] = A[M,K](bf16) * B[Nc,K]^T + bias (+epilogue)
// BW 1: B is bf16 -> global_load_lds staging for A and B (no cvt VALU).
// BW 0: B is f32  -> gld16 for A; B reg-load + cvt -> LDS.
// EPI 0: bias -> bf16 | 1: bias + f32 res -> f32 | 2: bias + GELU -> bf16
template <int EPI, int BW>
__device__ __forceinline__ void gemm_body(const u16* __restrict__ A,
                                          const void* __restrict__ B,
                                          const float* __restrict__ bias,
                                          const float* __restrict__ res,
                                          void* __restrict__ out,
                                          int m0, int n0, int Nc, int K) {
  __shared__ __align__(16) u16 Asm[128 * 32];
  __shared__ __align__(16) u16 Bsm[128 * 32];
  const int t = threadIdx.x;
  const int w = t >> 6, lane = t & 63;
  const int quad = lane >> 4, mr = lane & 15;
  const int wm = (w >> 1) * 64, wn = (w & 1) * 64;
  const int r = t >> 2, sseg = t & 3;

  f32x4 acc[4][4];
  const f32x4 zero4 = {0.f, 0.f, 0.f, 0.f};
#pragma unroll
  for (int i = 0; i < 4; ++i)
#pragma unroll
    for (int j = 0; j < 4; ++j) acc[i][j] = zero4;

  const u16* Ab = A + (size_t)(m0 + r) * K + sseg * 8;
  const u16* Bb16 = (const u16*)B + (size_t)(n0 + r) * K + sseg * 8;
  const float* Bb32 = (const float*)B + (size_t)(n0 + r) * K + sseg * 8;
  u16* AsmT = Asm + t * 8;  // lane-linear: wave-uniform base + lane*16B
  u16* BsmT = Bsm + t * 8;

  for (int k0 = 0; k0 < K; k0 += 32) {
    if (BW) {
      __syncthreads();  // all waves done reading previous tile
      gld16(Ab + k0, AsmT);
      gld16(Ab + k0 + (size_t)64 * K, AsmT + 2048);
      gld16(Bb16 + k0, BsmT);
      gld16(Bb16 + k0 + (size_t)64 * K, BsmT + 2048);
      __syncthreads();  // drains vmcnt (gld writes) before reads
    } else {
      float4 b0a = *(const float4*)(Bb32 + k0);
      float4 b0b = *(const float4*)(Bb32 + k0 + 4);
      float4 b1a = *(const float4*)(Bb32 + k0 + (size_t)64 * K);
      float4 b1b = *(const float4*)(Bb32 + k0 + (size_t)64 * K + 4);
      u16x8 b0 = cvt8(b0a, b0b);
      u16x8 b1 = cvt8(b1a, b1b);
      __syncthreads();  // all waves done reading previous tile
      gld16(Ab + k0, AsmT);
      gld16(Ab + k0 + (size_t)64 * K, AsmT + 2048);
      *(u16x8*)BsmT = b0;
      *(u16x8*)(BsmT + 2048) = b1;
      __syncthreads();  // drains vmcnt + lgkmcnt before reads
    }
    bf16x8 af[4], bfr[4];
#pragma unroll
    for (int i = 0; i < 4; ++i)
      af[i] = *(const bf16x8*)&Asm[(wm + i * 16 + mr) * 32 + quad * 8];
#pragma unroll
    for (int j = 0; j < 4; ++j)
      bfr[j] = *(const bf16x8*)&Bsm[(wn + j * 16 + mr) * 32 + quad * 8];
#pragma unroll
    for (int i = 0; i < 4; ++i)
#pragma unroll
      for (int j = 0; j < 4; ++j)
        acc[i][j] = __builtin_amdgcn_mfma_f32_16x16x32_bf16(af[i], bfr[j], acc[i][j], 0, 0, 0);
  }

  float* outf = (float*)out;
  u16* outb = (u16*)out;
#pragma unroll
  for (int j = 0; j < 4; ++j) {
    int n = n0 + wn + j * 16 + mr;
    float bv = bias[n];
#pragma unroll
    for (int i = 0; i < 4; ++i) {
      int mb = m0 + wm + i * 16 + quad * 4;
#pragma unroll
      for (int rr = 0; rr < 4; ++rr) {
        size_t off = (size_t)(mb + rr) * Nc + n;
        float v = acc[i][j][rr] + bv;
        if (EPI == 0) {
          outb[off] = f2bf(fin(v));
        } else if (EPI == 1) {
          outf[off] = fin(v + res[off]);
        } else {
          float g = 0.5f * v * (1.0f + erff(v * 0.70710678118654752f));
          outb[off] = f2bf(fin(g));
        }
      }
    }
  }
}

template <int EPI, int BW>
__global__ __launch_bounds__(256) void gemm_bt(const u16* __restrict__ A,
                                               const void* __restrict__ B,
                                               const float* __restrict__ bias,
                                               const float* __restrict__ res,
                                               void* __restrict__ out,
                                               int Nc, int K) {
  gemm_body<EPI, BW>(A, B, bias, res, out, blockIdx.y * 128, blockIdx.x * 128, Nc, K);
}

// fused QKV from bf16 wbf: grid.x in [0,6): sel = x>>1, n0 = (x&1)*128
__global__ __launch_bounds__(256) void gemm_qkv(const u16* __restrict__ A,
                                                const u16* __restrict__ wbf,
                                                const float* __restrict__ bq,
                                                const float* __restrict__ bk,
                                                const float* __restrict__ bv,
                                                u16* __restrict__ qo,
                                                u16* __restrict__ ko,
                                                u16* __restrict__ vo) {
  int sel = blockIdx.x >> 1;
  const u16* B = wbf + sel * 65536;
  const float* bias = (sel == 0) ? bq : ((sel == 1) ? bk : bv);
  u16* out = (sel == 0) ? qo : ((sel == 1) ? ko : vo);
  gemm_body<0, 1>(A, B, bias, nullptr, out, blockIdx.y * 128, (blockIdx.x & 1) * 128,
                  DIMS, DIMS);
}

// ---------------- gathered neighborhood attention (bf16 in/out) ----------------

__global__ __launch_bounds__(256) void attn_kernel(const u16* __restrict__ Q,
                                                   const u16* __restrict__ Kb,
                                                   const u16* __restrict__ Vb,
                                                   const int* __restrict__ nbr,
                                                   u16* __restrict__ out) {
  int t = blockIdx.x * 256 + threadIdx.x;
  int p = t >> 3, h = t & 7;
  const u16* qrow = Q + (size_t)p * DIMS + h * HDIM;
  float qf[32];
#pragma unroll
  for (int c = 0; c < 4; ++c) {
    u16x8 u = *(const u16x8*)(qrow + c * 8);
#pragma unroll
    for (int e = 0; e < 8; ++e) qf[c * 8 + e] = bf2f(u[e]);
  }
  int idx[KNN];
#pragma unroll
  for (int j = 0; j < KNN; ++j) {
    int ix = nbr[p * KNN + j];
    idx[j] = (ix < 0 || ix >= N_PTS) ? 0 : ix;  // fault guard
  }
  float sc[KNN];
#pragma unroll
  for (int j = 0; j < KNN; ++j) {
    const u16* kr = Kb + (size_t)idx[j] * DIMS + h * HDIM;
    float acc = 0.f;
#pragma unroll
    for (int c = 0; c < 4; ++c) {
      u16x8 u = *(const u16x8*)(kr + c * 8);
#pragma unroll
      for (int e = 0; e < 8; ++e) acc += qf[c * 8 + e] * bf2f(u[e]);
    }
    sc[j] = fin(acc * SCALE);
  }
  float mx = sc[0];
#pragma unroll
  for (int j = 1; j < KNN; ++j) mx = fmaxf(mx, sc[j]);
  float sum = 0.f;
#pragma unroll
  for (int j = 0; j < KNN; ++j) {
    sc[j] = expf(sc[j] - mx);
    sum += sc[j];
  }
  float inv = 1.f / fmaxf(sum, 1e-30f);
  float o[32];
#pragma unroll
  for (int d = 0; d < 32; ++d) o[d] = 0.f;
#pragma unroll
  for (int j = 0; j < KNN; ++j) {
    float wgt = sc[j] * inv;
    const u16* vr = Vb + (size_t)idx[j] * DIMS + h * HDIM;
#pragma unroll
    for (int c = 0; c < 4; ++c) {
      u16x8 u = *(const u16x8*)(vr + c * 8);
#pragma unroll
      for (int e = 0; e < 8; ++e) o[c * 8 + e] = fmaf(wgt, bf2f(u[e]), o[c * 8 + e]);
    }
  }
  u16* orow = out + (size_t)p * DIMS + h * HDIM;
#pragma unroll
  for (int c = 0; c < 4; ++c) {
    u16x8 u;
#pragma unroll
    for (int e = 0; e < 8; ++e) u[e] = f2bf(fin(o[c * 8 + e]));
    *(u16x8*)(orow + c * 8) = u;
  }
}

// ---------------- launch ----------------
// Workspace (peak 58.72 MiB == proven-safe footprint), liveness-reused:
//  A [0,16M):      x1f (t3+)            | earlier: qb [0,8M), kb [8,16M)
//  B [16M,48M):    hid (t5+)            | earlier (t0-t2):
//     +0       pos4 (256K, t0)
//     +262144  Mmin (8M, t0) -- overlaid by wbf (512K, t0.5-t3) after tau
//     +8650752 tau (64K) | +8716288 cnt (64K)
//     +8781824 surv (8M, t0) -- overlaid by vb (8M, t1-t2)
//     +17170432 ao (8M, t2-t3)
//     +25559040 nbr (1.25M, t0-t2)
//     +26869760 h (8M, t1; tail crosses into C, time-disjoint with h2)
//  C [48M,56M+...): h2 [50331648,58720256) (t4-t5)
extern "C" void kernel_launch(void* const* d_in, const int* in_sizes, int n_in,
                              void* d_out, int out_size, void* d_ws, size_t ws_size,
                              hipStream_t stream) {
  const float* x = (const float*)d_in[0];
  const float* positions = (const float*)d_in[1];
  const float* ln1_w = (const float*)d_in[2];
  const float* ln1_b = (const float*)d_in[3];
  const float* Wq = (const float*)d_in[4];
  const float* bq = (const float*)d_in[5];
  const float* Wk = (const float*)d_in[6];
  const float* bk = (const float*)d_in[7];
  const float* Wv = (const float*)d_in[8];
  const float* bv = (const float*)d_in[9];
  const float* Wo = (const float*)d_in[10];
  const float* bo = (const float*)d_in[11];
  const float* ln2_w = (const float*)d_in[12];
  const float* ln2_b = (const float*)d_in[13];
  const float* W1 = (const float*)d_in[14];
  const float* b1 = (const float*)d_in[15];
  const float* W2 = (const float*)d_in[16];
  const float* b2 = (const float*)d_in[17];

  char* w = (char*)d_ws;
  const size_t B0 = 16777216;
  float* x1f = (float*)(w + 0);                    // 16 MiB
  u16* hid = (u16*)(w + B0);                       // 32 MiB (t5+)
  u16* h2 = (u16*)(w + 50331648);                  // 8 MiB [50331648,58720256)
  // t0 scratch inside hid region
  float4* pos4 = (float4*)(w + B0);                // 256 KiB
  float* Mmin = (float*)(w + B0 + 262144);         // 8 MiB (dead after tau)
  u16* wbf = (u16*)(w + B0 + 262144);              // 512 KiB (overlays Mmin, t0.5-t3)
  float* tau = (float*)(w + B0 + 8650752);         // 64 KiB
  int* cnt = (int*)(w + B0 + 8716288);             // 64 KiB
  ull* surv = (ull*)(w + B0 + 8781824);            // 8 MiB (64 slots)
  int* nbr = (int*)(w + B0 + 25559040);            // 1.25 MiB (t0-t2)
  u16* h = (u16*)(w + B0 + 26869760);              // 8 MiB (t1 only)
  // phase reuse
  u16* qb = (u16*)(w + 0);                         // 8 MiB (t1-t2)
  u16* kb = (u16*)(w + 8388608);                   // 8 MiB (t1-t2)
  u16* vb = (u16*)(w + B0 + 8781824);              // 8 MiB (over dead surv)
  u16* ao = (u16*)(w + B0 + 17170432);             // 8 MiB (t2-t3)

  // t0: kNN pipeline (128 shards for occupancy; tau proof holds per-shard-count)
  knn_init<<<dim3(N_PTS / 256), dim3(256), 0, stream>>>(positions, pos4, cnt, nbr);
  knn_shardmin<<<dim3(NSHARD, 16), dim3(256), 0, stream>>>(pos4, Mmin);
  knn_tau<<<dim3(64), dim3(256), 0, stream>>>(Mmin, tau);
  conv_w<<<dim3(256), dim3(256), 0, stream>>>(Wq, Wk, Wv, Wo, wbf);  // Mmin dead
  knn_collect<<<dim3(NSHARD, 16), dim3(256), 0, stream>>>(pos4, tau, cnt, surv);
  knn_rank<<<dim3(N_PTS), dim3(64), 0, stream>>>(cnt, surv, nbr);

  // t1: LN1 + fused QKV (bf16 weights, full gld16 staging)
  ln_kernel<<<dim3(N_PTS / 4), dim3(256), 0, stream>>>(x, ln1_w, ln1_b, h);
  gemm_qkv<<<dim3(6, 128), dim3(256), 0, stream>>>(h, wbf, bq, bk, bv, qb, kb, vb);

  // t2: attention; t3: output proj (+residual 1) -> f32
  attn_kernel<<<dim3(N_PTS * HEADS / 256), dim3(256), 0, stream>>>(qb, kb, vb, nbr, ao);
  gemm_bt<1, 1><<<dim3(2, 128), dim3(256), 0, stream>>>(ao, wbf + 196608, bo, x, x1f,
                                                        DIMS, DIMS);

  // t4: LN2; t5/t6: MLP (+residual 2) -> f32 out
  ln_kernel<<<dim3(N_PTS / 4), dim3(256), 0, stream>>>(x1f, ln2_w, ln2_b, h2);
  gemm_bt<2, 0><<<dim3(8, 128), dim3(256), 0, stream>>>(h2, W1, b1, nullptr, hid,
                                                        MLPH, DIMS);
  gemm_bt<1, 0><<<dim3(2, 128), dim3(256), 0, stream>>>(hid, W2, b2, x1f,
                                                        (float*)d_out, DIMS, MLPH);
}

// Round 11
// 350.138 us; speedup vs baseline: 1.0843x; 1.0843x over previous
//
#include <hip/hip_runtime.h>
#include <math.h>

#define N_PTS 16384
#define DIMS 256
#define HEADS 8
#define HDIM 32
#define KNN 20
#define MLPH 1024
#define NSHARD 128
#define SHARDC 128
#define SURV_SLOTS 64
#define SCALE 0.17677669529663687f  // 32^-0.5
#define WEXT_OFF 58720256            // 56 MiB: proven-safe footprint end
#define WEXT_BYTES 1572864           // QKVO 512K + W1 512K + W2 512K (bf16)

typedef unsigned short u16;
typedef unsigned long long ull;
typedef __attribute__((ext_vector_type(8))) short bf16x8;
typedef __attribute__((ext_vector_type(8))) unsigned short u16x8;
typedef __attribute__((ext_vector_type(4))) float f32x4;

__device__ __forceinline__ float bf2f(u16 u) {
  return __uint_as_float(((unsigned int)u) << 16);
}
__device__ __forceinline__ u16 f2bf(float f) {
  unsigned int u = __float_as_uint(f);
  u += 0x7fffu + ((u >> 16) & 1u);
  return (u16)(u >> 16);
}
__device__ __forceinline__ float fin(float v) {
  return __builtin_isfinite(v) ? v : 0.f;
}
__device__ __forceinline__ float dist2(float4 a, float4 b) {
  float dx = a.x - b.x, dy = a.y - b.y, dz = a.z - b.z;
  return dx * dx + dy * dy + dz * dz;
}
__device__ __forceinline__ u16x8 cvt8(float4 a, float4 b) {
  u16x8 o;
  o[0] = f2bf(a.x); o[1] = f2bf(a.y); o[2] = f2bf(a.z); o[3] = f2bf(a.w);
  o[4] = f2bf(b.x); o[5] = f2bf(b.y); o[6] = f2bf(b.z); o[7] = f2bf(b.w);
  return o;
}
// async global->LDS, 16 B/lane; LDS dest = wave-uniform base + lane*16.
__device__ __forceinline__ void gld16(const u16* g, u16* l) {
  __builtin_amdgcn_global_load_lds(
      (const __attribute__((address_space(1))) unsigned int*)g,
      (__attribute__((address_space(3))) unsigned int*)l, 16, 0, 0);
}

// ---------------- init + full weight pre-convert (primary, big-ws path) ----
// grid 768: idx<16384 also does kNN init; conv groups: [0,64K) QKVO,
// [64K,128K) W1, [128K,192K) W2 (float4 groups, row-major copies).

__global__ __launch_bounds__(256) void knn_init_conv(
    const float* __restrict__ pos, float4* __restrict__ pos4,
    int* __restrict__ cnt, int* __restrict__ nbr,
    const float* __restrict__ Wq, const float* __restrict__ Wk,
    const float* __restrict__ Wv, const float* __restrict__ Wo,
    const float* __restrict__ W1, const float* __restrict__ W2,
    u16* __restrict__ ext) {
  int idx = blockIdx.x * 256 + threadIdx.x;
  if (idx < N_PTS) {
    cnt[idx] = 0;
#pragma unroll
    for (int j = 0; j < KNN; ++j) nbr[idx * KNN + j] = 0;
    float x = fin(pos[3 * idx]), y = fin(pos[3 * idx + 1]), z = fin(pos[3 * idx + 2]);
    pos4[idx] = make_float4(x, y, z, x * x + y * y + z * z);
  }
  const float* src;
  u16* dst;
  int loc;
  if (idx < 65536) {
    int mat = idx >> 14; loc = idx & 16383;
    src = (mat == 0) ? Wq : ((mat == 1) ? Wk : ((mat == 2) ? Wv : Wo));
    dst = ext + mat * 65536;
  } else if (idx < 131072) {
    loc = idx - 65536; src = W1; dst = ext + 262144;
  } else {
    loc = idx - 131072; src = W2; dst = ext + 524288;
  }
  float4 v = ((const float4*)src)[loc];
  ushort4 o;
  o.x = f2bf(v.x); o.y = f2bf(v.y); o.z = f2bf(v.z); o.w = f2bf(v.w);
  ((ushort4*)dst)[loc] = o;
}

// ---------------- fallback (small ws): r10 kernels ----------------

__global__ __launch_bounds__(256) void knn_init(const float* __restrict__ pos,
                                                float4* __restrict__ pos4,
                                                int* __restrict__ cnt,
                                                int* __restrict__ nbr) {
  int i = blockIdx.x * 256 + threadIdx.x;
  cnt[i] = 0;
#pragma unroll
  for (int j = 0; j < KNN; ++j) nbr[i * KNN + j] = 0;
  float x = fin(pos[3 * i]), y = fin(pos[3 * i + 1]), z = fin(pos[3 * i + 2]);
  pos4[i] = make_float4(x, y, z, x * x + y * y + z * z);
}

__global__ __launch_bounds__(256) void conv_w(const float* __restrict__ Wq,
                                              const float* __restrict__ Wk,
                                              const float* __restrict__ Wv,
                                              const float* __restrict__ Wo,
                                              u16* __restrict__ wbf) {
  int idx = blockIdx.x * 256 + threadIdx.x;
  int mat = idx >> 14, loc = idx & 16383;
  const float* src = (mat == 0) ? Wq : ((mat == 1) ? Wk : ((mat == 2) ? Wv : Wo));
  float4 v = ((const float4*)src)[loc];
  ushort4 o;
  o.x = f2bf(v.x); o.y = f2bf(v.y); o.z = f2bf(v.z); o.w = f2bf(v.w);
  ((ushort4*)(wbf + mat * 65536))[loc] = o;
}

// ---------------- kNN ----------------
// d' = |c|^2 - 2 q.c screening metric (per-query shift of true d).
// 128 shards: at most 20 shard-minima < d'_(21) => tau >= d'_(21).

__global__ __launch_bounds__(256) void knn_shardmin(const float4* __restrict__ pos4,
                                                    float* __restrict__ Mmin) {
  __shared__ float4 cp[SHARDC];
  int shard = blockIdx.x;
  int qbase = blockIdx.y * 1024 + threadIdx.x;
  if (threadIdx.x < SHARDC) cp[threadIdx.x] = pos4[shard * SHARDC + threadIdx.x];
  float m2x[4], m2y[4], m2z[4], mn[4];
#pragma unroll
  for (int k = 0; k < 4; ++k) {
    float4 qp = pos4[qbase + k * 256];
    m2x[k] = -2.f * qp.x; m2y[k] = -2.f * qp.y; m2z[k] = -2.f * qp.z;
    mn[k] = 3.4e38f;
  }
  __syncthreads();
#pragma unroll 4
  for (int c = 0; c < SHARDC; ++c) {
    float4 cc = cp[c];
#pragma unroll
    for (int k = 0; k < 4; ++k) {
      float t = fmaf(m2z[k], cc.z, cc.w);
      t = fmaf(m2y[k], cc.y, t);
      t = fmaf(m2x[k], cc.x, t);
      mn[k] = fminf(mn[k], t);
    }
  }
#pragma unroll
  for (int k = 0; k < 4; ++k) Mmin[shard * N_PTS + qbase + k * 256] = mn[k];
}

// tau via 4 threads/query (r10 lesson: 1-thread tau = 0.25 waves/SIMD,
// latency-bound). Each thread sinks 32 shard minima into a sorted top-21;
// exact 21st of all 128 = 21st pop of a 4-way merge of the sorted arrays.
__global__ __launch_bounds__(256) void knn_tau4(const float* __restrict__ Mmin,
                                                float* __restrict__ tau) {
  __shared__ float sm[64][4][21];
  int tid = threadIdx.x;
  int sub = tid & 3, qi = tid >> 2;
  int q = blockIdx.x * 64 + qi;
  float a[21];
#pragma unroll
  for (int j = 0; j < 21; ++j) a[j] = 3.4e38f;
  int s0 = sub * 32;
  for (int s = s0; s < s0 + 32; ++s) {
    float v = Mmin[s * N_PTS + q];
    a[20] = fminf(a[20], v);
#pragma unroll
    for (int j = 20; j >= 1; --j) {  // sink keeps a[] sorted ascending
      float lo = fminf(a[j - 1], a[j]), hi = fmaxf(a[j - 1], a[j]);
      a[j - 1] = lo; a[j] = hi;
    }
  }
#pragma unroll
  for (int j = 0; j < 21; ++j) sm[qi][sub][j] = a[j];
  __syncthreads();
  if (sub == 0) {
    int i0 = 0, i1 = 0, i2 = 0, i3 = 0;
    float tv = 3.4e38f;
#pragma unroll
    for (int n = 0; n < 21; ++n) {  // 21 pops of 4-way sorted merge
      float v0 = sm[qi][0][i0], v1 = sm[qi][1][i1];
      float v2 = sm[qi][2][i2], v3 = sm[qi][3][i3];
      float m = fminf(fminf(v0, v1), fminf(v2, v3));
      tv = m;
      if (m == v0) ++i0;
      else if (m == v1) ++i1;
      else if (m == v2) ++i2;
      else ++i3;
    }
    tau[q] = tv;
  }
}

// grid (128 shards, 16 q-groups), 4 queries/thread. Branchless hot loop
// (r8), 3-op if-converted record (r9); cold path materializes exact keys.
__global__ __launch_bounds__(256) void knn_collect(const float4* __restrict__ pos4,
                                                   const float* __restrict__ tau,
                                                   int* __restrict__ cnt,
                                                   ull* __restrict__ surv) {
  __shared__ float4 cp[SHARDC];
  int cbase = blockIdx.x * SHARDC;
  int qbase = blockIdx.y * 1024 + threadIdx.x;
  if (threadIdx.x < SHARDC) cp[threadIdx.x] = pos4[cbase + threadIdx.x];
  float4 qp[4];
  float m2x[4], m2y[4], m2z[4], tq[4];
  unsigned int packed[4];
  int hitcnt[4];
#pragma unroll
  for (int k = 0; k < 4; ++k) {
    qp[k] = pos4[qbase + k * 256];
    m2x[k] = -2.f * qp[k].x; m2y[k] = -2.f * qp[k].y; m2z[k] = -2.f * qp[k].z;
    tq[k] = tau[qbase + k * 256] + 2e-4f;
    packed[k] = 0; hitcnt[k] = 0;
  }
  __syncthreads();
#pragma unroll 4
  for (int c = 0; c < SHARDC; ++c) {
    float4 cc = cp[c];
#pragma unroll
    for (int k = 0; k < 4; ++k) {
      float t = fmaf(m2z[k], cc.z, cc.w);
      t = fmaf(m2y[k], cc.y, t);
      t = fmaf(m2x[k], cc.x, t);
      bool hit = (t <= tq[k]);
      packed[k] = hit ? ((packed[k] << 8) | (unsigned)c) : packed[k];
      hitcnt[k] += hit ? 1 : 0;
    }
  }
#pragma unroll
  for (int k = 0; k < 4; ++k) {
    int hc = hitcnt[k];
    if (hc > 0) {
      int q = qbase + k * 256;
      if (hc <= 4) {
        int slot = atomicAdd(&cnt[q], hc);
        for (int i = 0; i < hc; ++i) {
          int c = (packed[k] >> (8 * i)) & 255;
          float d = dist2(qp[k], cp[c]);
          ull key = ((ull)__float_as_uint(d) << 32) | (unsigned)(cbase + c);
          if (slot + i < SURV_SLOTS)
            surv[(size_t)q * SURV_SLOTS + slot + i] = key;
        }
      } else {
        for (int c = 0; c < SHARDC; ++c) {
          float4 cc = cp[c];
          float t = fmaf(m2z[k], cc.z, cc.w);
          t = fmaf(m2y[k], cc.y, t);
          t = fmaf(m2x[k], cc.x, t);
          if (t <= tq[k]) {
            float d = dist2(qp[k], cc);
            ull key = ((ull)__float_as_uint(d) << 32) | (unsigned)(cbase + c);
            int slot = atomicAdd(&cnt[q], 1);
            if (slot < SURV_SLOTS) surv[(size_t)q * SURV_SLOTS + slot] = key;
          }
        }
      }
    }
  }
}

__global__ void knn_rank(const int* __restrict__ cnt,
                         const ull* __restrict__ surv,
                         int* __restrict__ nbr) {
  __shared__ ull s[SURV_SLOTS];
  int q = blockIdx.x;
  int c = min(cnt[q], SURV_SLOTS);
  for (int i = threadIdx.x; i < c; i += 64) s[i] = surv[(size_t)q * SURV_SLOTS + i];
  __syncthreads();
  for (int i = threadIdx.x; i < c; i += 64) {
    ull key = s[i];
    int rank = 0;
    for (int j = 0; j < c; ++j) rank += (s[j] < key);
    if (rank >= 1 && rank <= KNN) nbr[q * KNN + rank - 1] = (int)(key & 0xffffffffu);
  }
}

// ---------------- LayerNorm (wave per row): f32 in -> bf16 out ----------------

__global__ __launch_bounds__(256) void ln_kernel(const float* __restrict__ xin,
                                                 const float* __restrict__ w,
                                                 const float* __restrict__ b,
                                                 u16* __restrict__ out) {
  int row = blockIdx.x * 4 + (threadIdx.x >> 6);
  int lane = threadIdx.x & 63;
  float4 u = ((const float4*)(xin + row * DIMS))[lane];
  float f[4] = {fin(u.x), fin(u.y), fin(u.z), fin(u.w)};
  float sum = f[0] + f[1] + f[2] + f[3];
  float sq = f[0] * f[0] + f[1] * f[1] + f[2] * f[2] + f[3] * f[3];
#pragma unroll
  for (int o = 32; o > 0; o >>= 1) {
    sum += __shfl_xor(sum, o);
    sq += __shfl_xor(sq, o);
  }
  float mean = sum * (1.f / 256.f);
  float var = fmaxf(sq * (1.f / 256.f) - mean * mean, 0.f);
  float rs = rsqrtf(var + 1e-5f);
  float4 wv = ((const float4*)w)[lane];
  float4 bv = ((const float4*)b)[lane];
  ushort4 o4;
  o4.x = f2bf(fin((f[0] - mean) * rs * wv.x + bv.x));
  o4.y = f2bf(fin((f[1] - mean) * rs * wv.y + bv.y));
  o4.z = f2bf(fin((f[2] - mean) * rs * wv.z + bv.z));
  o4.w = f2bf(fin((f[3] - mean) * rs * wv.w + bv.w));
  ((ushort4*)(out + row * DIMS))[lane] = o4;
}

// ---------------- MFMA GEMM body ----------------
// BW 1: B bf16 -> gld16 staging for A and B. BW 0: B f32 -> reg cvt.
// EPI 0: bias->bf16 | 1: bias + f32 res -> f32 | 2: bias + GELU -> bf16
template <int EPI, int BW>
__device__ __forceinline__ void gemm_body(const u16* __restrict__ A,
                                          const void* __restrict__ B,
                                          const float* __restrict__ bias,
                                          const float* __restrict__ res,
                                          void* __restrict__ out,
                                          int m0, int n0, int Nc, int K) {
  __shared__ __align__(16) u16 Asm[128 * 32];
  __shared__ __align__(16) u16 Bsm[128 * 32];
  const int t = threadIdx.x;
  const int w = t >> 6, lane = t & 63;
  const int quad = lane >> 4, mr = lane & 15;
  const int wm = (w >> 1) * 64, wn = (w & 1) * 64;
  const int r = t >> 2, sseg = t & 3;

  f32x4 acc[4][4];
  const f32x4 zero4 = {0.f, 0.f, 0.f, 0.f};
#pragma unroll
  for (int i = 0; i < 4; ++i)
#pragma unroll
    for (int j = 0; j < 4; ++j) acc[i][j] = zero4;

  const u16* Ab = A + (size_t)(m0 + r) * K + sseg * 8;
  const u16* Bb16 = (const u16*)B + (size_t)(n0 + r) * K + sseg * 8;
  const float* Bb32 = (const float*)B + (size_t)(n0 + r) * K + sseg * 8;
  u16* AsmT = Asm + t * 8;
  u16* BsmT = Bsm + t * 8;

  for (int k0 = 0; k0 < K; k0 += 32) {
    if (BW) {
      __syncthreads();
      gld16(Ab + k0, AsmT);
      gld16(Ab + k0 + (size_t)64 * K, AsmT + 2048);
      gld16(Bb16 + k0, BsmT);
      gld16(Bb16 + k0 + (size_t)64 * K, BsmT + 2048);
      __syncthreads();
    } else {
      float4 b0a = *(const float4*)(Bb32 + k0);
      float4 b0b = *(const float4*)(Bb32 + k0 + 4);
      float4 b1a = *(const float4*)(Bb32 + k0 + (size_t)64 * K);
      float4 b1b = *(const float4*)(Bb32 + k0 + (size_t)64 * K + 4);
      u16x8 b0 = cvt8(b0a, b0b);
      u16x8 b1 = cvt8(b1a, b1b);
      __syncthreads();
      gld16(Ab + k0, AsmT);
      gld16(Ab + k0 + (size_t)64 * K, AsmT + 2048);
      *(u16x8*)BsmT = b0;
      *(u16x8*)(BsmT + 2048) = b1;
      __syncthreads();
    }
    bf16x8 af[4], bfr[4];
#pragma unroll
    for (int i = 0; i < 4; ++i)
      af[i] = *(const bf16x8*)&Asm[(wm + i * 16 + mr) * 32 + quad * 8];
#pragma unroll
    for (int j = 0; j < 4; ++j)
      bfr[j] = *(const bf16x8*)&Bsm[(wn + j * 16 + mr) * 32 + quad * 8];
#pragma unroll
    for (int i = 0; i < 4; ++i)
#pragma unroll
      for (int j = 0; j < 4; ++j)
        acc[i][j] = __builtin_amdgcn_mfma_f32_16x16x32_bf16(af[i], bfr[j], acc[i][j], 0, 0, 0);
  }

  float* outf = (float*)out;
  u16* outb = (u16*)out;
#pragma unroll
  for (int j = 0; j < 4; ++j) {
    int n = n0 + wn + j * 16 + mr;
    float bv = bias[n];
#pragma unroll
    for (int i = 0; i < 4; ++i) {
      int mb = m0 + wm + i * 16 + quad * 4;
#pragma unroll
      for (int rr = 0; rr < 4; ++rr) {
        size_t off = (size_t)(mb + rr) * Nc + n;
        float v = acc[i][j][rr] + bv;
        if (EPI == 0) {
          outb[off] = f2bf(fin(v));
        } else if (EPI == 1) {
          outf[off] = fin(v + res[off]);
        } else {
          float g = 0.5f * v * (1.0f + erff(v * 0.70710678118654752f));
          outb[off] = f2bf(fin(g));
        }
      }
    }
  }
}

template <int EPI, int BW>
__global__ __launch_bounds__(256) void gemm_bt(const u16* __restrict__ A,
                                               const void* __restrict__ B,
                                               const float* __restrict__ bias,
                                               const float* __restrict__ res,
                                               void* __restrict__ out,
                                               int Nc, int K) {
  gemm_body<EPI, BW>(A, B, bias, res, out, blockIdx.y * 128, blockIdx.x * 128, Nc, K);
}

__global__ __launch_bounds__(256) void gemm_qkv(const u16* __restrict__ A,
                                                const u16* __restrict__ wbf,
                                                const float* __restrict__ bq,
                                                const float* __restrict__ bk,
                                                const float* __restrict__ bv,
                                                u16* __restrict__ qo,
                                                u16* __restrict__ ko,
                                                u16* __restrict__ vo) {
  int sel = blockIdx.x >> 1;
  const u16* B = wbf + sel * 65536;
  const float* bias = (sel == 0) ? bq : ((sel == 1) ? bk : bv);
  u16* out = (sel == 0) ? qo : ((sel == 1) ? ko : vo);
  gemm_body<0, 1>(A, B, bias, nullptr, out, blockIdx.y * 128, (blockIdx.x & 1) * 128,
                  DIMS, DIMS);
}

// ---------------- gathered neighborhood attention ----------------

__global__ __launch_bounds__(256) void attn_kernel(const u16* __restrict__ Q,
                                                   const u16* __restrict__ Kb,
                                                   const u16* __restrict__ Vb,
                                                   const int* __restrict__ nbr,
                                                   u16* __restrict__ out) {
  int t = blockIdx.x * 256 + threadIdx.x;
  int p = t >> 3, h = t & 7;
  const u16* qrow = Q + (size_t)p * DIMS + h * HDIM;
  float qf[32];
#pragma unroll
  for (int c = 0; c < 4; ++c) {
    u16x8 u = *(const u16x8*)(qrow + c * 8);
#pragma unroll
    for (int e = 0; e < 8; ++e) qf[c * 8 + e] = bf2f(u[e]);
  }
  int idx[KNN];
#pragma unroll
  for (int j = 0; j < KNN; ++j) {
    int ix = nbr[p * KNN + j];
    idx[j] = (ix < 0 || ix >= N_PTS) ? 0 : ix;
  }
  float sc[KNN];
#pragma unroll
  for (int j = 0; j < KNN; ++j) {
    const u16* kr = Kb + (size_t)idx[j] * DIMS + h * HDIM;
    float acc = 0.f;
#pragma unroll
    for (int c = 0; c < 4; ++c) {
      u16x8 u = *(const u16x8*)(kr + c * 8);
#pragma unroll
      for (int e = 0; e < 8; ++e) acc += qf[c * 8 + e] * bf2f(u[e]);
    }
    sc[j] = fin(acc * SCALE);
  }
  float mx = sc[0];
#pragma unroll
  for (int j = 1; j < KNN; ++j) mx = fmaxf(mx, sc[j]);
  float sum = 0.f;
#pragma unroll
  for (int j = 0; j < KNN; ++j) {
    sc[j] = expf(sc[j] - mx);
    sum += sc[j];
  }
  float inv = 1.f / fmaxf(sum, 1e-30f);
  float o[32];
#pragma unroll
  for (int d = 0; d < 32; ++d) o[d] = 0.f;
#pragma unroll
  for (int j = 0; j < KNN; ++j) {
    float wgt = sc[j] * inv;
    const u16* vr = Vb + (size_t)idx[j] * DIMS + h * HDIM;
#pragma unroll
    for (int c = 0; c < 4; ++c) {
      u16x8 u = *(const u16x8*)(vr + c * 8);
#pragma unroll
      for (int e = 0; e < 8; ++e) o[c * 8 + e] = fmaf(wgt, bf2f(u[e]), o[c * 8 + e]);
    }
  }
  u16* orow = out + (size_t)p * DIMS + h * HDIM;
#pragma unroll
  for (int c = 0; c < 4; ++c) {
    u16x8 u;
#pragma unroll
    for (int e = 0; e < 8; ++e) u[e] = f2bf(fin(o[c * 8 + e]));
    *(u16x8*)(orow + c * 8) = u;
  }
}

// ---------------- launch ----------------
// Base footprint 56 MiB (proven safe). If ws_size >= 57.5 MiB, bf16 weights
// (QKVO+W1+W2) live past 56 MiB and all GEMMs take the gld16/BW=1 path;
// else exact r10 fallback (QKVO bf16 in dead-Mmin region, MLP BW=0).
extern "C" void kernel_launch(void* const* d_in, const int* in_sizes, int n_in,
                              void* d_out, int out_size, void* d_ws, size_t ws_size,
                              hipStream_t stream) {
  const float* x = (const float*)d_in[0];
  const float* positions = (const float*)d_in[1];
  const float* ln1_w = (const float*)d_in[2];
  const float* ln1_b = (const float*)d_in[3];
  const float* Wq = (const float*)d_in[4];
  const float* bq = (const float*)d_in[5];
  const float* Wk = (const float*)d_in[6];
  const float* bk = (const float*)d_in[7];
  const float* Wv = (const float*)d_in[8];
  const float* bv = (const float*)d_in[9];
  const float* Wo = (const float*)d_in[10];
  const float* bo = (const float*)d_in[11];
  const float* ln2_w = (const float*)d_in[12];
  const float* ln2_b = (const float*)d_in[13];
  const float* W1 = (const float*)d_in[14];
  const float* b1 = (const float*)d_in[15];
  const float* W2 = (const float*)d_in[16];
  const float* b2 = (const float*)d_in[17];

  char* w = (char*)d_ws;
  const size_t B0 = 16777216;
  float* x1f = (float*)(w + 0);                    // 16 MiB
  u16* hid = (u16*)(w + B0);                       // 32 MiB (t5+)
  u16* h2 = (u16*)(w + 50331648);                  // 8 MiB -> ends 56 MiB
  float4* pos4 = (float4*)(w + B0);                // 256 KiB (t0)
  float* Mmin = (float*)(w + B0 + 262144);         // 8 MiB (dead after tau)
  u16* wbfH = (u16*)(w + B0 + 262144);             // 512 KiB (fallback QKVO)
  float* tau = (float*)(w + B0 + 8650752);         // 64 KiB
  int* cnt = (int*)(w + B0 + 8716288);             // 64 KiB
  ull* surv = (ull*)(w + B0 + 8781824);            // 8 MiB
  int* nbr = (int*)(w + B0 + 25559040);            // 1.25 MiB
  u16* h = (u16*)(w + B0 + 26869760);              // 8 MiB (t1)
  u16* qb = (u16*)(w + 0);                         // 8 MiB (t1-t2)
  u16* kb = (u16*)(w + 8388608);                   // 8 MiB (t1-t2)
  u16* vb = (u16*)(w + B0 + 8781824);              // 8 MiB (over dead surv)
  u16* ao = (u16*)(w + B0 + 17170432);             // 8 MiB (t2-t3)
  u16* wext = (u16*)(w + WEXT_OFF);                // 1.5 MiB beyond 56 MiB
  const bool big = ws_size >= (size_t)WEXT_OFF + WEXT_BYTES;

  // t0: kNN pipeline (+ weight conversion)
  if (big) {
    knn_init_conv<<<dim3(768), dim3(256), 0, stream>>>(
        positions, pos4, cnt, nbr, Wq, Wk, Wv, Wo, W1, W2, wext);
  } else {
    knn_init<<<dim3(N_PTS / 256), dim3(256), 0, stream>>>(positions, pos4, cnt, nbr);
  }
  knn_shardmin<<<dim3(NSHARD, 16), dim3(256), 0, stream>>>(pos4, Mmin);
  knn_tau4<<<dim3(N_PTS / 64), dim3(256), 0, stream>>>(Mmin, tau);
  if (!big) conv_w<<<dim3(256), dim3(256), 0, stream>>>(Wq, Wk, Wv, Wo, wbfH);
  knn_collect<<<dim3(NSHARD, 16), dim3(256), 0, stream>>>(pos4, tau, cnt, surv);
  knn_rank<<<dim3(N_PTS), dim3(64), 0, stream>>>(cnt, surv, nbr);

  const u16* qkvw = big ? wext : wbfH;

  // t1: LN1 + fused QKV
  ln_kernel<<<dim3(N_PTS / 4), dim3(256), 0, stream>>>(x, ln1_w, ln1_b, h);
  gemm_qkv<<<dim3(6, 128), dim3(256), 0, stream>>>(h, qkvw, bq, bk, bv, qb, kb, vb);

  // t2: attention; t3: output proj (+residual 1) -> f32
  attn_kernel<<<dim3(N_PTS * HEADS / 256), dim3(256), 0, stream>>>(qb, kb, vb, nbr, ao);
  gemm_bt<1, 1><<<dim3(2, 128), dim3(256), 0, stream>>>(ao, qkvw + 196608, bo, x, x1f,
                                                        DIMS, DIMS);

  // t4: LN2; t5/t6: MLP (+residual 2) -> f32 out
  ln_kernel<<<dim3(N_PTS / 4), dim3(256), 0, stream>>>(x1f, ln2_w, ln2_b, h2);
  if (big) {
    gemm_bt<2, 1><<<dim3(8, 128), dim3(256), 0, stream>>>(h2, wext + 262144, b1,
                                                          nullptr, hid, MLPH, DIMS);
    gemm_bt<1, 1><<<dim3(2, 128), dim3(256), 0, stream>>>(hid, wext + 524288, b2, x1f,
                                                          (float*)d_out, DIMS, MLPH);
  } else {
    gemm_bt<2, 0><<<dim3(8, 128), dim3(256), 0, stream>>>(h2, W1, b1, nullptr, hid,
                                                          MLPH, DIMS);
    gemm_bt<1, 0><<<dim3(2, 128), dim3(256), 0, stream>>>(hid, W2, b2, x1f,
                                                          (float*)d_out, DIMS, MLPH);
  }
}

// Round 13
// 349.680 us; speedup vs baseline: 1.0857x; 1.0013x over previous
//
#include <hip/hip_runtime.h>
#include <math.h>

#define N_PTS 16384
#define DIMS 256
#define HEADS 8
#define HDIM 32
#define KNN 20
#define MLPH 1024
#define NSHARD 128
#define SHARDC 128
#define SURV_SLOTS 64
#define SCALE 0.17677669529663687f  // 32^-0.5
#define WEXT_OFF 58720256            // 56 MiB: proven-safe footprint end
#define WEXT_BYTES 1572864           // QKVO 512K + W1 512K + W2 512K (bf16)

typedef unsigned short u16;
typedef unsigned long long ull;
typedef __attribute__((ext_vector_type(8))) short bf16x8;
typedef __attribute__((ext_vector_type(8))) unsigned short u16x8;
typedef __attribute__((ext_vector_type(4))) float f32x4;

__device__ __forceinline__ float bf2f(u16 u) {
  return __uint_as_float(((unsigned int)u) << 16);
}
__device__ __forceinline__ u16 f2bf(float f) {
  unsigned int u = __float_as_uint(f);
  u += 0x7fffu + ((u >> 16) & 1u);
  return (u16)(u >> 16);
}
__device__ __forceinline__ float fin(float v) {
  return __builtin_isfinite(v) ? v : 0.f;
}
__device__ __forceinline__ float dist2(float4 a, float4 b) {
  float dx = a.x - b.x, dy = a.y - b.y, dz = a.z - b.z;
  return dx * dx + dy * dy + dz * dz;
}
__device__ __forceinline__ u16x8 cvt8(float4 a, float4 b) {
  u16x8 o;
  o[0] = f2bf(a.x); o[1] = f2bf(a.y); o[2] = f2bf(a.z); o[3] = f2bf(a.w);
  o[4] = f2bf(b.x); o[5] = f2bf(b.y); o[6] = f2bf(b.z); o[7] = f2bf(b.w);
  return o;
}
// async global->LDS, 16 B/lane; LDS dest = wave-uniform base + lane*16.
__device__ __forceinline__ void gld16(const u16* g, u16* l) {
  __builtin_amdgcn_global_load_lds(
      (const __attribute__((address_space(1))) unsigned int*)g,
      (__attribute__((address_space(3))) unsigned int*)l, 16, 0, 0);
}

// ---------------- init + full weight pre-convert (primary, big-ws path) ----

__global__ __launch_bounds__(256) void knn_init_conv(
    const float* __restrict__ pos, float4* __restrict__ pos4,
    int* __restrict__ cnt, int* __restrict__ nbr,
    const float* __restrict__ Wq, const float* __restrict__ Wk,
    const float* __restrict__ Wv, const float* __restrict__ Wo,
    const float* __restrict__ W1, const float* __restrict__ W2,
    u16* __restrict__ ext) {
  int idx = blockIdx.x * 256 + threadIdx.x;
  if (idx < N_PTS) {
    cnt[idx] = 0;
#pragma unroll
    for (int j = 0; j < KNN; ++j) nbr[idx * KNN + j] = 0;
    float x = fin(pos[3 * idx]), y = fin(pos[3 * idx + 1]), z = fin(pos[3 * idx + 2]);
    pos4[idx] = make_float4(x, y, z, x * x + y * y + z * z);
  }
  const float* src;
  u16* dst;
  int loc;
  if (idx < 65536) {
    int mat = idx >> 14; loc = idx & 16383;
    src = (mat == 0) ? Wq : ((mat == 1) ? Wk : ((mat == 2) ? Wv : Wo));
    dst = ext + mat * 65536;
  } else if (idx < 131072) {
    loc = idx - 65536; src = W1; dst = ext + 262144;
  } else {
    loc = idx - 131072; src = W2; dst = ext + 524288;
  }
  float4 v = ((const float4*)src)[loc];
  ushort4 o;
  o.x = f2bf(v.x); o.y = f2bf(v.y); o.z = f2bf(v.z); o.w = f2bf(v.w);
  ((ushort4*)dst)[loc] = o;
}

// ---------------- fallback (small ws) ----------------

__global__ __launch_bounds__(256) void knn_init(const float* __restrict__ pos,
                                                float4* __restrict__ pos4,
                                                int* __restrict__ cnt,
                                                int* __restrict__ nbr) {
  int i = blockIdx.x * 256 + threadIdx.x;
  cnt[i] = 0;
#pragma unroll
  for (int j = 0; j < KNN; ++j) nbr[i * KNN + j] = 0;
  float x = fin(pos[3 * i]), y = fin(pos[3 * i + 1]), z = fin(pos[3 * i + 2]);
  pos4[i] = make_float4(x, y, z, x * x + y * y + z * z);
}

__global__ __launch_bounds__(256) void conv_w(const float* __restrict__ Wq,
                                              const float* __restrict__ Wk,
                                              const float* __restrict__ Wv,
                                              const float* __restrict__ Wo,
                                              u16* __restrict__ wbf) {
  int idx = blockIdx.x * 256 + threadIdx.x;
  int mat = idx >> 14, loc = idx & 16383;
  const float* src = (mat == 0) ? Wq : ((mat == 1) ? Wk : ((mat == 2) ? Wv : Wo));
  float4 v = ((const float4*)src)[loc];
  ushort4 o;
  o.x = f2bf(v.x); o.y = f2bf(v.y); o.z = f2bf(v.z); o.w = f2bf(v.w);
  ((ushort4*)(wbf + mat * 65536))[loc] = o;
}

// ---------------- kNN ----------------
// d' = |c|^2 - 2 q.c screening metric (per-query shift of true d).
// 128 shards: at most 20 shard-minima < d'_(21) => tau >= d'_(21).

__global__ __launch_bounds__(256) void knn_shardmin(const float4* __restrict__ pos4,
                                                    float* __restrict__ Mmin) {
  __shared__ float4 cp[SHARDC];
  int shard = blockIdx.x;
  int qbase = blockIdx.y * 1024 + threadIdx.x;
  if (threadIdx.x < SHARDC) cp[threadIdx.x] = pos4[shard * SHARDC + threadIdx.x];
  float m2x[4], m2y[4], m2z[4], mn[4];
#pragma unroll
  for (int k = 0; k < 4; ++k) {
    float4 qp = pos4[qbase + k * 256];
    m2x[k] = -2.f * qp.x; m2y[k] = -2.f * qp.y; m2z[k] = -2.f * qp.z;
    mn[k] = 3.4e38f;
  }
  __syncthreads();
#pragma unroll 4
  for (int c = 0; c < SHARDC; ++c) {
    float4 cc = cp[c];
#pragma unroll
    for (int k = 0; k < 4; ++k) {
      float t = fmaf(m2z[k], cc.z, cc.w);
      t = fmaf(m2y[k], cc.y, t);
      t = fmaf(m2x[k], cc.x, t);
      mn[k] = fminf(mn[k], t);
    }
  }
#pragma unroll
  for (int k = 0; k < 4; ++k) Mmin[shard * N_PTS + qbase + k * 256] = mn[k];
}

// tau via 4 threads/query (r10 lesson: 1-thread tau = 0.25 waves/SIMD,
// latency-bound). Each thread sinks 32 shard minima into a sorted top-21;
// exact 21st of all 128 = 21st pop of a 4-way merge of the sorted arrays.
__global__ __launch_bounds__(256) void knn_tau4(const float* __restrict__ Mmin,
                                                float* __restrict__ tau) {
  __shared__ float sm[64][4][21];
  int tid = threadIdx.x;
  int sub = tid & 3, qi = tid >> 2;
  int q = blockIdx.x * 64 + qi;
  float a[21];
#pragma unroll
  for (int j = 0; j < 21; ++j) a[j] = 3.4e38f;
  int s0 = sub * 32;
  for (int s = s0; s < s0 + 32; ++s) {
    float v = Mmin[s * N_PTS + q];
    a[20] = fminf(a[20], v);
#pragma unroll
    for (int j = 20; j >= 1; --j) {  // sink keeps a[] sorted ascending
      float lo = fminf(a[j - 1], a[j]), hi = fmaxf(a[j - 1], a[j]);
      a[j - 1] = lo; a[j] = hi;
    }
  }
#pragma unroll
  for (int j = 0; j < 21; ++j) sm[qi][sub][j] = a[j];
  __syncthreads();
  if (sub == 0) {
    int i0 = 0, i1 = 0, i2 = 0, i3 = 0;
    float tv = 3.4e38f;
#pragma unroll
    for (int n = 0; n < 21; ++n) {  // 21 pops of 4-way sorted merge
      float v0 = sm[qi][0][i0], v1 = sm[qi][1][i1];
      float v2 = sm[qi][2][i2], v3 = sm[qi][3][i3];
      float m = fminf(fminf(v0, v1), fminf(v2, v3));
      tv = m;
      if (m == v0) ++i0;
      else if (m == v1) ++i1;
      else if (m == v2) ++i2;
      else ++i3;
    }
    tau[q] = tv;
  }
}

// grid (128 shards, 16 q-groups), 4 queries/thread. Branchless hot loop
// (r8), 3-op if-converted record (r9); cold path materializes exact keys.
__global__ __launch_bounds__(256) void knn_collect(const float4* __restrict__ pos4,
                                                   const float* __restrict__ tau,
                                                   int* __restrict__ cnt,
                                                   ull* __restrict__ surv) {
  __shared__ float4 cp[SHARDC];
  int cbase = blockIdx.x * SHARDC;
  int qbase = blockIdx.y * 1024 + threadIdx.x;
  if (threadIdx.x < SHARDC) cp[threadIdx.x] = pos4[cbase + threadIdx.x];
  float4 qp[4];
  float m2x[4], m2y[4], m2z[4], tq[4];
  unsigned int packed[4];
  int hitcnt[4];
#pragma unroll
  for (int k = 0; k < 4; ++k) {
    qp[k] = pos4[qbase + k * 256];
    m2x[k] = -2.f * qp[k].x; m2y[k] = -2.f * qp[k].y; m2z[k] = -2.f * qp[k].z;
    tq[k] = tau[qbase + k * 256] + 2e-4f;
    packed[k] = 0; hitcnt[k] = 0;
  }
  __syncthreads();
#pragma unroll 4
  for (int c = 0; c < SHARDC; ++c) {
    float4 cc = cp[c];
#pragma unroll
    for (int k = 0; k < 4; ++k) {
      float t = fmaf(m2z[k], cc.z, cc.w);
      t = fmaf(m2y[k], cc.y, t);
      t = fmaf(m2x[k], cc.x, t);
      bool hit = (t <= tq[k]);
      packed[k] = hit ? ((packed[k] << 8) | (unsigned)c) : packed[k];
      hitcnt[k] += hit ? 1 : 0;
    }
  }
#pragma unroll
  for (int k = 0; k < 4; ++k) {
    int hc = hitcnt[k];
    if (hc > 0) {
      int q = qbase + k * 256;
      if (hc <= 4) {
        int slot = atomicAdd(&cnt[q], hc);
        for (int i = 0; i < hc; ++i) {
          int c = (packed[k] >> (8 * i)) & 255;
          float d = dist2(qp[k], cp[c]);
          ull key = ((ull)__float_as_uint(d) << 32) | (unsigned)(cbase + c);
          if (slot + i < SURV_SLOTS)
            surv[(size_t)q * SURV_SLOTS + slot + i] = key;
        }
      } else {
        for (int c = 0; c < SHARDC; ++c) {
          float4 cc = cp[c];
          float t = fmaf(m2z[k], cc.z, cc.w);
          t = fmaf(m2y[k], cc.y, t);
          t = fmaf(m2x[k], cc.x, t);
          if (t <= tq[k]) {
            float d = dist2(qp[k], cc);
            ull key = ((ull)__float_as_uint(d) << 32) | (unsigned)(cbase + c);
            int slot = atomicAdd(&cnt[q], 1);
            if (slot < SURV_SLOTS) surv[(size_t)q * SURV_SLOTS + slot] = key;
          }
        }
      }
    }
  }
}

__global__ void knn_rank(const int* __restrict__ cnt,
                         const ull* __restrict__ surv,
                         int* __restrict__ nbr) {
  __shared__ ull s[SURV_SLOTS];
  int q = blockIdx.x;
  int c = min(cnt[q], SURV_SLOTS);
  for (int i = threadIdx.x; i < c; i += 64) s[i] = surv[(size_t)q * SURV_SLOTS + i];
  __syncthreads();
  for (int i = threadIdx.x; i < c; i += 64) {
    ull key = s[i];
    int rank = 0;
    for (int j = 0; j < c; ++j) rank += (s[j] < key);
    if (rank >= 1 && rank <= KNN) nbr[q * KNN + rank - 1] = (int)(key & 0xffffffffu);
  }
}

// ---------------- LayerNorm (wave per row): f32 in -> bf16 out ----------------

__global__ __launch_bounds__(256) void ln_kernel(const float* __restrict__ xin,
                                                 const float* __restrict__ w,
                                                 const float* __restrict__ b,
                                                 u16* __restrict__ out) {
  int row = blockIdx.x * 4 + (threadIdx.x >> 6);
  int lane = threadIdx.x & 63;
  float4 u = ((const float4*)(xin + row * DIMS))[lane];
  float f[4] = {fin(u.x), fin(u.y), fin(u.z), fin(u.w)};
  float sum = f[0] + f[1] + f[2] + f[3];
  float sq = f[0] * f[0] + f[1] * f[1] + f[2] * f[2] + f[3] * f[3];
#pragma unroll
  for (int o = 32; o > 0; o >>= 1) {
    sum += __shfl_xor(sum, o);
    sq += __shfl_xor(sq, o);
  }
  float mean = sum * (1.f / 256.f);
  float var = fmaxf(sq * (1.f / 256.f) - mean * mean, 0.f);
  float rs = rsqrtf(var + 1e-5f);
  float4 wv = ((const float4*)w)[lane];
  float4 bv = ((const float4*)b)[lane];
  ushort4 o4;
  o4.x = f2bf(fin((f[0] - mean) * rs * wv.x + bv.x));
  o4.y = f2bf(fin((f[1] - mean) * rs * wv.y + bv.y));
  o4.z = f2bf(fin((f[2] - mean) * rs * wv.z + bv.z));
  o4.w = f2bf(fin((f[3] - mean) * rs * wv.w + bv.w));
  ((ushort4*)(out + row * DIMS))[lane] = o4;
}

// ---------------- MFMA GEMM body ----------------
// BW 1: B bf16 -> gld16 staging for A and B. BW 0: B f32 -> reg cvt.
// EPI 0: bias->bf16 | 1: bias + f32 res -> f32 | 2: bias + GELU -> bf16
template <int EPI, int BW>
__device__ __forceinline__ void gemm_body(const u16* __restrict__ A,
                                          const void* __restrict__ B,
                                          const float* __restrict__ bias,
                                          const float* __restrict__ res,
                                          void* __restrict__ out,
                                          int m0, int n0, int Nc, int K) {
  __shared__ __align__(16) u16 Asm[128 * 32];
  __shared__ __align__(16) u16 Bsm[128 * 32];
  const int t = threadIdx.x;
  const int w = t >> 6, lane = t & 63;
  const int quad = lane >> 4, mr = lane & 15;
  const int wm = (w >> 1) * 64, wn = (w & 1) * 64;
  const int r = t >> 2, sseg = t & 3;

  f32x4 acc[4][4];
  const f32x4 zero4 = {0.f, 0.f, 0.f, 0.f};
#pragma unroll
  for (int i = 0; i < 4; ++i)
#pragma unroll
    for (int j = 0; j < 4; ++j) acc[i][j] = zero4;

  const u16* Ab = A + (size_t)(m0 + r) * K + sseg * 8;
  const u16* Bb16 = (const u16*)B + (size_t)(n0 + r) * K + sseg * 8;
  const float* Bb32 = (const float*)B + (size_t)(n0 + r) * K + sseg * 8;
  u16* AsmT = Asm + t * 8;
  u16* BsmT = Bsm + t * 8;

  for (int k0 = 0; k0 < K; k0 += 32) {
    if (BW) {
      __syncthreads();
      gld16(Ab + k0, AsmT);
      gld16(Ab + k0 + (size_t)64 * K, AsmT + 2048);
      gld16(Bb16 + k0, BsmT);
      gld16(Bb16 + k0 + (size_t)64 * K, BsmT + 2048);
      __syncthreads();
    } else {
      float4 b0a = *(const float4*)(Bb32 + k0);
      float4 b0b = *(const float4*)(Bb32 + k0 + 4);
      float4 b1a = *(const float4*)(Bb32 + k0 + (size_t)64 * K);
      float4 b1b = *(const float4*)(Bb32 + k0 + (size_t)64 * K + 4);
      u16x8 b0 = cvt8(b0a, b0b);
      u16x8 b1 = cvt8(b1a, b1b);
      __syncthreads();
      gld16(Ab + k0, AsmT);
      gld16(Ab + k0 + (size_t)64 * K, AsmT + 2048);
      *(u16x8*)BsmT = b0;
      *(u16x8*)(BsmT + 2048) = b1;
      __syncthreads();
    }
    bf16x8 af[4], bfr[4];
#pragma unroll
    for (int i = 0; i < 4; ++i)
      af[i] = *(const bf16x8*)&Asm[(wm + i * 16 + mr) * 32 + quad * 8];
#pragma unroll
    for (int j = 0; j < 4; ++j)
      bfr[j] = *(const bf16x8*)&Bsm[(wn + j * 16 + mr) * 32 + quad * 8];
#pragma unroll
    for (int i = 0; i < 4; ++i)
#pragma unroll
      for (int j = 0; j < 4; ++j)
        acc[i][j] = __builtin_amdgcn_mfma_f32_16x16x32_bf16(af[i], bfr[j], acc[i][j], 0, 0, 0);
  }

  float* outf = (float*)out;
  u16* outb = (u16*)out;
#pragma unroll
  for (int j = 0; j < 4; ++j) {
    int n = n0 + wn + j * 16 + mr;
    float bv = bias[n];
#pragma unroll
    for (int i = 0; i < 4; ++i) {
      int mb = m0 + wm + i * 16 + quad * 4;
#pragma unroll
      for (int rr = 0; rr < 4; ++rr) {
        size_t off = (size_t)(mb + rr) * Nc + n;
        float v = acc[i][j][rr] + bv;
        if (EPI == 0) {
          outb[off] = f2bf(fin(v));
        } else if (EPI == 1) {
          outf[off] = fin(v + res[off]);
        } else {
          float g = 0.5f * v * (1.0f + erff(v * 0.70710678118654752f));
          outb[off] = f2bf(fin(g));
        }
      }
    }
  }
}

template <int EPI, int BW>
__global__ __launch_bounds__(256) void gemm_bt(const u16* __restrict__ A,
                                               const void* __restrict__ B,
                                               const float* __restrict__ bias,
                                               const float* __restrict__ res,
                                               void* __restrict__ out,
                                               int Nc, int K) {
  gemm_body<EPI, BW>(A, B, bias, res, out, blockIdx.y * 128, blockIdx.x * 128, Nc, K);
}

__global__ __launch_bounds__(256) void gemm_qkv(const u16* __restrict__ A,
                                                const u16* __restrict__ wbf,
                                                const float* __restrict__ bq,
                                                const float* __restrict__ bk,
                                                const float* __restrict__ bv,
                                                u16* __restrict__ qo,
                                                u16* __restrict__ ko,
                                                u16* __restrict__ vo) {
  int sel = blockIdx.x >> 1;
  const u16* B = wbf + sel * 65536;
  const float* bias = (sel == 0) ? bq : ((sel == 1) ? bk : bv);
  u16* out = (sel == 0) ? qo : ((sel == 1) ? ko : vo);
  gemm_body<0, 1>(A, B, bias, nullptr, out, blockIdx.y * 128, (blockIdx.x & 1) * 128,
                  DIMS, DIMS);
}

// ---------------- gathered neighborhood attention ----------------

__global__ __launch_bounds__(256) void attn_kernel(const u16* __restrict__ Q,
                                                   const u16* __restrict__ Kb,
                                                   const u16* __restrict__ Vb,
                                                   const int* __restrict__ nbr,
                                                   u16* __restrict__ out) {
  int t = blockIdx.x * 256 + threadIdx.x;
  int p = t >> 3, h = t & 7;
  const u16* qrow = Q + (size_t)p * DIMS + h * HDIM;
  float qf[32];
#pragma unroll
  for (int c = 0; c < 4; ++c) {
    u16x8 u = *(const u16x8*)(qrow + c * 8);
#pragma unroll
    for (int e = 0; e < 8; ++e) qf[c * 8 + e] = bf2f(u[e]);
  }
  int idx[KNN];
#pragma unroll
  for (int j = 0; j < KNN; ++j) {
    int ix = nbr[p * KNN + j];
    idx[j] = (ix < 0 || ix >= N_PTS) ? 0 : ix;
  }
  float sc[KNN];
#pragma unroll
  for (int j = 0; j < KNN; ++j) {
    const u16* kr = Kb + (size_t)idx[j] * DIMS + h * HDIM;
    float acc = 0.f;
#pragma unroll
    for (int c = 0; c < 4; ++c) {
      u16x8 u = *(const u16x8*)(kr + c * 8);
#pragma unroll
      for (int e = 0; e < 8; ++e) acc += qf[c * 8 + e] * bf2f(u[e]);
    }
    sc[j] = fin(acc * SCALE);
  }
  float mx = sc[0];
#pragma unroll
  for (int j = 1; j < KNN; ++j) mx = fmaxf(mx, sc[j]);
  float sum = 0.f;
#pragma unroll
  for (int j = 0; j < KNN; ++j) {
    sc[j] = expf(sc[j] - mx);
    sum += sc[j];
  }
  float inv = 1.f / fmaxf(sum, 1e-30f);
  float o[32];
#pragma unroll
  for (int d = 0; d < 32; ++d) o[d] = 0.f;
#pragma unroll
  for (int j = 0; j < KNN; ++j) {
    float wgt = sc[j] * inv;
    const u16* vr = Vb + (size_t)idx[j] * DIMS + h * HDIM;
#pragma unroll
    for (int c = 0; c < 4; ++c) {
      u16x8 u = *(const u16x8*)(vr + c * 8);
#pragma unroll
      for (int e = 0; e < 8; ++e) o[c * 8 + e] = fmaf(wgt, bf2f(u[e]), o[c * 8 + e]);
    }
  }
  u16* orow = out + (size_t)p * DIMS + h * HDIM;
#pragma unroll
  for (int c = 0; c < 4; ++c) {
    u16x8 u;
#pragma unroll
    for (int e = 0; e < 8; ++e) u[e] = f2bf(fin(o[c * 8 + e]));
    *(u16x8*)(orow + c * 8) = u;
  }
}

// ---------------- launch ----------------
// Base footprint 56 MiB (proven safe); bf16 weights past 56 MiB when ws
// allows (big path), else r10 fallback (QKVO bf16 in dead-Mmin region,
// MLP BW=0).
extern "C" void kernel_launch(void* const* d_in, const int* in_sizes, int n_in,
                              void* d_out, int out_size, void* d_ws, size_t ws_size,
                              hipStream_t stream) {
  const float* x = (const float*)d_in[0];
  const float* positions = (const float*)d_in[1];
  const float* ln1_w = (const float*)d_in[2];
  const float* ln1_b = (const float*)d_in[3];
  const float* Wq = (const float*)d_in[4];
  const float* bq = (const float*)d_in[5];
  const float* Wk = (const float*)d_in[6];
  const float* bk = (const float*)d_in[7];
  const float* Wv = (const float*)d_in[8];
  const float* bv = (const float*)d_in[9];
  const float* Wo = (const float*)d_in[10];
  const float* bo = (const float*)d_in[11];
  const float* ln2_w = (const float*)d_in[12];
  const float* ln2_b = (const float*)d_in[13];
  const float* W1 = (const float*)d_in[14];
  const float* b1 = (const float*)d_in[15];
  const float* W2 = (const float*)d_in[16];
  const float* b2 = (const float*)d_in[17];

  char* w = (char*)d_ws;
  const size_t B0 = 16777216;
  float* x1f = (float*)(w + 0);                    // 16 MiB
  u16* hid = (u16*)(w + B0);                       // 32 MiB (t5+)
  u16* h2 = (u16*)(w + 50331648);                  // 8 MiB -> ends 56 MiB
  float4* pos4 = (float4*)(w + B0);                // 256 KiB (t0)
  float* Mmin = (float*)(w + B0 + 262144);         // 8 MiB (dead after tau4)
  u16* wbfH = (u16*)(w + B0 + 262144);             // 512 KiB (fallback QKVO)
  float* tau = (float*)(w + B0 + 8650752);         // 64 KiB
  int* cnt = (int*)(w + B0 + 8716288);             // 64 KiB
  ull* surv = (ull*)(w + B0 + 8781824);            // 8 MiB
  int* nbr = (int*)(w + B0 + 25559040);            // 1.25 MiB
  u16* h = (u16*)(w + B0 + 26869760);              // 8 MiB (t1)
  u16* qb = (u16*)(w + 0);                         // 8 MiB (t1-t2)
  u16* kb = (u16*)(w + 8388608);                   // 8 MiB (t1-t2)
  u16* vb = (u16*)(w + B0 + 8781824);              // 8 MiB (over dead surv)
  u16* ao = (u16*)(w + B0 + 17170432);             // 8 MiB (t2-t3)
  u16* wext = (u16*)(w + WEXT_OFF);                // 1.5 MiB beyond 56 MiB
  const bool big = ws_size >= (size_t)WEXT_OFF + WEXT_BYTES;

  // t0: kNN pipeline (+ weight conversion)
  if (big) {
    knn_init_conv<<<dim3(768), dim3(256), 0, stream>>>(
        positions, pos4, cnt, nbr, Wq, Wk, Wv, Wo, W1, W2, wext);
  } else {
    knn_init<<<dim3(N_PTS / 256), dim3(256), 0, stream>>>(positions, pos4, cnt, nbr);
  }
  knn_shardmin<<<dim3(NSHARD, 16), dim3(256), 0, stream>>>(pos4, Mmin);
  knn_tau4<<<dim3(N_PTS / 64), dim3(256), 0, stream>>>(Mmin, tau);
  if (!big) conv_w<<<dim3(256), dim3(256), 0, stream>>>(Wq, Wk, Wv, Wo, wbfH);
  knn_collect<<<dim3(NSHARD, 16), dim3(256), 0, stream>>>(pos4, tau, cnt, surv);
  knn_rank<<<dim3(N_PTS), dim3(64), 0, stream>>>(cnt, surv, nbr);

  const u16* qkvw = big ? wext : wbfH;

  // t1: LN1 + fused QKV
  ln_kernel<<<dim3(N_PTS / 4), dim3(256), 0, stream>>>(x, ln1_w, ln1_b, h);
  gemm_qkv<<<dim3(6, 128), dim3(256), 0, stream>>>(h, qkvw, bq, bk, bv, qb, kb, vb);

  // t2: attention; t3: output proj (+residual 1) -> f32
  attn_kernel<<<dim3(N_PTS * HEADS / 256), dim3(256), 0, stream>>>(qb, kb, vb, nbr, ao);
  gemm_bt<1, 1><<<dim3(2, 128), dim3(256), 0, stream>>>(ao, qkvw + 196608, bo, x, x1f,
                                                        DIMS, DIMS);

  // t4: LN2; t5/t6: MLP (+residual 2) -> f32 out
  ln_kernel<<<dim3(N_PTS / 4), dim3(256), 0, stream>>>(x1f, ln2_w, ln2_b, h2);
  if (big) {
    gemm_bt<2, 1><<<dim3(8, 128), dim3(256), 0, stream>>>(h2, wext + 262144, b1,
                                                          nullptr, hid, MLPH, DIMS);
    gemm_bt<1, 1><<<dim3(2, 128), dim3(256), 0, stream>>>(hid, wext + 524288, b2, x1f,
                                                          (float*)d_out, DIMS, MLPH);
  } else {
    gemm_bt<2, 0><<<dim3(8, 128), dim3(256), 0, stream>>>(h2, W1, b1, nullptr, hid,
                                                          MLPH, DIMS);
    gemm_bt<1, 0><<<dim3(2, 128), dim3(256), 0, stream>>>(hid, W2, b2, x1f,
                                                          (float*)d_out, DIMS, MLPH);
  }
}